// Round 1
// baseline (481.655 us; speedup 1.0000x reference)
//
#include <hip/hip_runtime.h>

// Unpool (conv_transpose2d, single-1 depthwise kernel), stride 2.
// in:  (8, 256, 112, 112) fp32;  out: (8, 256, 224, 224) fp32,
// out[:,:,::2,::2] = in, rest 0.
//
// v2: 4x16B chunks per thread (vs 1x8B). Chunk c (a float4 of input):
//   r = c/28 (input flat row), j = c%28
//   even out row: 2x float4 @ out + 448r + 8j   ({x,0,y,0}, {z,0,w,0})
//   odd  out row: 2x float4 zeros @ +224
// 4 independent chunks per thread, loads issued first (4 outstanding
// 16B/lane loads), zero-stores issued before load results are needed.
// Every output element written exactly once (d_out is poisoned).

__global__ __launch_bounds__(256) void unpool_wide4(
    const float4* __restrict__ in, float* __restrict__ out,
    unsigned n4, unsigned tstride)
{
    const unsigned t = blockIdx.x * blockDim.x + threadIdx.x;
    const float4 z4 = make_float4(0.0f, 0.0f, 0.0f, 0.0f);

    const unsigned c0 = t;
    const unsigned c1 = t + tstride;
    const unsigned c2 = t + 2u * tstride;
    const unsigned c3 = t + 3u * tstride;

    const bool p0 = c0 < n4, p1 = c1 < n4, p2 = c2 < n4, p3 = c3 < n4;

    // Issue all loads first: 4 outstanding 16B loads per lane.
    float4 v0, v1, v2, v3;
    if (p0) v0 = in[c0];
    if (p1) v1 = in[c1];
    if (p2) v2 = in[c2];
    if (p3) v3 = in[c3];

    unsigned r0 = c0 / 28u, j0 = c0 - r0 * 28u;
    unsigned r1 = c1 / 28u, j1 = c1 - r1 * 28u;
    unsigned r2 = c2 / 28u, j2 = c2 - r2 * 28u;
    unsigned r3 = c3 / 28u, j3 = c3 - r3 * 28u;

    float* b0 = out + 448u * r0 + 8u * j0;
    float* b1 = out + 448u * r1 + 8u * j1;
    float* b2 = out + 448u * r2 + 8u * j2;
    float* b3 = out + 448u * r3 + 8u * j3;

    // Zero-stores (odd output rows): no dependence on the loads — these
    // flow out while the loads are still in flight.
    if (p0) { reinterpret_cast<float4*>(b0 + 224)[0] = z4;
              reinterpret_cast<float4*>(b0 + 228)[0] = z4; }
    if (p1) { reinterpret_cast<float4*>(b1 + 224)[0] = z4;
              reinterpret_cast<float4*>(b1 + 228)[0] = z4; }
    if (p2) { reinterpret_cast<float4*>(b2 + 224)[0] = z4;
              reinterpret_cast<float4*>(b2 + 228)[0] = z4; }
    if (p3) { reinterpret_cast<float4*>(b3 + 224)[0] = z4;
              reinterpret_cast<float4*>(b3 + 228)[0] = z4; }

    // Data stores (even output rows), interleaved pattern x,0,y,0|z,0,w,0.
    if (p0) { reinterpret_cast<float4*>(b0)[0] = make_float4(v0.x, 0.f, v0.y, 0.f);
              reinterpret_cast<float4*>(b0)[1] = make_float4(v0.z, 0.f, v0.w, 0.f); }
    if (p1) { reinterpret_cast<float4*>(b1)[0] = make_float4(v1.x, 0.f, v1.y, 0.f);
              reinterpret_cast<float4*>(b1)[1] = make_float4(v1.z, 0.f, v1.w, 0.f); }
    if (p2) { reinterpret_cast<float4*>(b2)[0] = make_float4(v2.x, 0.f, v2.y, 0.f);
              reinterpret_cast<float4*>(b2)[1] = make_float4(v2.z, 0.f, v2.w, 0.f); }
    if (p3) { reinterpret_cast<float4*>(b3)[0] = make_float4(v3.x, 0.f, v3.y, 0.f);
              reinterpret_cast<float4*>(b3)[1] = make_float4(v3.z, 0.f, v3.w, 0.f); }
}

extern "C" void kernel_launch(void* const* d_in, const int* in_sizes, int n_in,
                              void* d_out, int out_size, void* d_ws, size_t ws_size,
                              hipStream_t stream)
{
    const float4* x = (const float4*)d_in[0];
    float* out      = (float*)d_out;

    // in_sizes[0] = 25,690,112 input floats -> n4 = 6,422,528 float4 chunks.
    unsigned n4      = (unsigned)in_sizes[0] / 4u;
    unsigned threads = (n4 + 3u) / 4u;            // 4 chunks per thread
    int      block   = 256;
    int      grid    = (int)((threads + block - 1) / block);   // 6272 blocks
    unsigned tstride = (unsigned)grid * (unsigned)block;       // 1,605,632

    unpool_wide4<<<grid, block, 0, stream>>>(x, out, n4, tstride);
}

// Round 4
// 477.463 us; speedup vs baseline: 1.0088x; 1.0088x over previous
//
#include <hip/hip_runtime.h>

// Unpool (conv_transpose2d, single-1 depthwise kernel), stride 2.
// in:  (8, 256, 112, 112) fp32;  out: (8, 256, 224, 224) fp32,
// out[:,:,::2,::2] = in, rest 0.
//
// v3c: per-instruction wave-contiguous unit mapping (unit u = one float2 of
// input -> one float4 of even-row output + one float4 of odd-row zeros):
//   r = u/56 (input flat row), j = u%56
//   data:  out + 448r + 4j      = {x, 0, y, 0}
//   zeros: out + 448r + 224 + 4j
// ILP: each thread handles 4 units spaced by blockDim (256), so every
// load/store instruction across a wave stays contiguous (512B loads, 1KB
// stores, 128B-aligned segments). 7 iterations per block -> 1792 blocks
// (n = 12,845,056 = 1792 * 7 * 1024 exactly => fast path has no bounds
// checks; guarded path kept for safety). Zero-stores issued while loads are
// in flight. Nontemporal stores via clang ext_vector_type (HIP float4 is a
// class type __builtin_nontemporal_store rejects). Every output element
// written exactly once (d_out is poisoned).

typedef float f32x4 __attribute__((ext_vector_type(4)));

#define UNITS_PER_ITER 1024u   // 256 threads * 4 units
#define ITERS 7u

__global__ __launch_bounds__(256) void unpool_ilp4(
    const float2* __restrict__ in, float* __restrict__ out, unsigned n)
{
    const unsigned tid = threadIdx.x;
    unsigned u_base = blockIdx.x * (UNITS_PER_ITER * ITERS) + tid;

    const f32x4 z4 = {0.0f, 0.0f, 0.0f, 0.0f};

    if (u_base + (ITERS - 1u) * UNITS_PER_ITER + 768u < n) {
        // Fast path: whole block in range (always true for the bench shape).
        #pragma unroll
        for (unsigned it = 0; it < ITERS; ++it, u_base += UNITS_PER_ITER) {
            const unsigned u0 = u_base;
            const unsigned u1 = u_base + 256u;
            const unsigned u2 = u_base + 512u;
            const unsigned u3 = u_base + 768u;

            // 4 outstanding 8B loads per lane, each instruction contiguous
            // across the wave.
            const float2 v0 = in[u0];
            const float2 v1 = in[u1];
            const float2 v2 = in[u2];
            const float2 v3 = in[u3];

            const unsigned r0 = u0 / 56u, j0 = u0 - r0 * 56u;
            const unsigned r1 = u1 / 56u, j1 = u1 - r1 * 56u;
            const unsigned r2 = u2 / 56u, j2 = u2 - r2 * 56u;
            const unsigned r3 = u3 / 56u, j3 = u3 - r3 * 56u;

            float* b0 = out + 448u * r0 + 4u * j0;
            float* b1 = out + 448u * r1 + 4u * j1;
            float* b2 = out + 448u * r2 + 4u * j2;
            float* b3 = out + 448u * r3 + 4u * j3;

            // Odd-row zeros: independent of loads — issue while loads fly.
            __builtin_nontemporal_store(z4, reinterpret_cast<f32x4*>(b0 + 224));
            __builtin_nontemporal_store(z4, reinterpret_cast<f32x4*>(b1 + 224));
            __builtin_nontemporal_store(z4, reinterpret_cast<f32x4*>(b2 + 224));
            __builtin_nontemporal_store(z4, reinterpret_cast<f32x4*>(b3 + 224));

            // Even-row data.
            const f32x4 d0 = {v0.x, 0.f, v0.y, 0.f};
            const f32x4 d1 = {v1.x, 0.f, v1.y, 0.f};
            const f32x4 d2 = {v2.x, 0.f, v2.y, 0.f};
            const f32x4 d3 = {v3.x, 0.f, v3.y, 0.f};
            __builtin_nontemporal_store(d0, reinterpret_cast<f32x4*>(b0));
            __builtin_nontemporal_store(d1, reinterpret_cast<f32x4*>(b1));
            __builtin_nontemporal_store(d2, reinterpret_cast<f32x4*>(b2));
            __builtin_nontemporal_store(d3, reinterpret_cast<f32x4*>(b3));
        }
    } else {
        // Guarded tail path (not taken for the bench shape).
        for (unsigned it = 0; it < ITERS; ++it, u_base += UNITS_PER_ITER) {
            #pragma unroll
            for (unsigned k = 0; k < 4u; ++k) {
                const unsigned u = u_base + k * 256u;
                if (u >= n) continue;
                const float2 v = in[u];
                const unsigned r = u / 56u, j = u - r * 56u;
                float* b = out + 448u * r + 4u * j;
                const f32x4 d = {v.x, 0.f, v.y, 0.f};
                __builtin_nontemporal_store(z4, reinterpret_cast<f32x4*>(b + 224));
                __builtin_nontemporal_store(d,  reinterpret_cast<f32x4*>(b));
            }
        }
    }
}

extern "C" void kernel_launch(void* const* d_in, const int* in_sizes, int n_in,
                              void* d_out, int out_size, void* d_ws, size_t ws_size,
                              hipStream_t stream)
{
    const float2* x = (const float2*)d_in[0];
    float* out      = (float*)d_out;

    // in_sizes[0] = 25,690,112 floats -> n = 12,845,056 float2 units.
    unsigned n      = (unsigned)in_sizes[0] / 2u;
    unsigned biters = (n + UNITS_PER_ITER - 1u) / UNITS_PER_ITER;  // 12,544
    int      grid   = (int)((biters + ITERS - 1u) / ITERS);        // 1,792
    int      block  = 256;

    unpool_ilp4<<<grid, block, 0, stream>>>(x, out, n);
}